// Round 6
// baseline (560.100 us; speedup 1.0000x reference)
//
#include <hip/hip_runtime.h>

#define TPB 256            // node-pass / count block size
#define BTPB 512           // k_bin block size
#define SORT_TPB 1024      // k_sort block size (== S)
#define ATPB 512           // k_agg block size (8 waves)
#define LOG_S 10
#define S (1 << LOG_S)     // 1024-node range per bucket
#define RMAX 256
#define CHUNK 4096         // edges per k_bin block

// CSR pipeline: edges binned by dst range (R = ceil(n/S), S=1024) into packed
// uint32 (local_dst << 18 | src)  [needs n <= 2^18]. k_sort counting-sorts each
// bucket by local dst -> csr[] holds src sorted by dst, rowptr/cnt per node.
// Aggregations are then atomic-free: wave-per-node coalesced csr + gather +
// shuffle reduce, with the GCN epilogue fused. deg comes free from cnt.

__global__ void k_zero(int* __restrict__ p, int m) {
    int i = blockIdx.x * blockDim.x + threadIdx.x;
    if (i < m) p[i] = 0;
}

__global__ __launch_bounds__(TPB) void k_count(const int* __restrict__ dst, int e,
                                               int R, int* __restrict__ ghist) {
    __shared__ int h[RMAX];
    int t = threadIdx.x;
    if (t < RMAX) h[t] = 0;
    __syncthreads();
    int e4 = e >> 2;
    const int4* d4p = (const int4*)dst;
    int stride = gridDim.x * blockDim.x;
    for (int i = blockIdx.x * blockDim.x + t; i < e4; i += stride) {
        int4 d = d4p[i];
        atomicAdd(&h[d.x >> LOG_S], 1);
        atomicAdd(&h[d.y >> LOG_S], 1);
        atomicAdd(&h[d.z >> LOG_S], 1);
        atomicAdd(&h[d.w >> LOG_S], 1);
    }
    for (int i = (e4 << 2) + blockIdx.x * blockDim.x + t; i < e; i += stride)
        atomicAdd(&h[dst[i] >> LOG_S], 1);
    __syncthreads();
    if (t < R && h[t]) atomicAdd(&ghist[t], h[t]);
}

__global__ void k_scan(const int* __restrict__ ghist, int R,
                       int* __restrict__ boff, int* __restrict__ blen,
                       int* __restrict__ cursors) {
    if (threadIdx.x == 0 && blockIdx.x == 0) {
        int off = 0;
        for (int r = 0; r < R; r++) {
            boff[r] = off;
            blen[r] = ghist[r];
            cursors[r] = off;
            off = (off + ghist[r] + 3) & ~3;   // 16B-aligned bucket bases
        }
        boff[R] = off;
    }
}

__global__ __launch_bounds__(BTPB) void k_bin(const int* __restrict__ dst,
                                              const int* __restrict__ src, int e,
                                              int R, int* __restrict__ cursors,
                                              unsigned* __restrict__ buckets) {
    __shared__ unsigned lpack[CHUNK];
    __shared__ unsigned char lrr[CHUNK];
    __shared__ unsigned stage[CHUNK];
    __shared__ int h[RMAX], lofs[RMAX + 1], gbase[RMAX], c2[RMAX];
    int t = threadIdx.x;
    int b0 = blockIdx.x * CHUNK;
    int m = min(CHUNK, e - b0);
    if (t < RMAX) { h[t] = 0; c2[t] = 0; }
    __syncthreads();
    for (int j = t; j < m; j += BTPB) {
        int d = dst[b0 + j];
        int s = src[b0 + j];
        int r = d >> LOG_S;
        lpack[j] = ((unsigned)(d - (r << LOG_S)) << 18) | (unsigned)s;
        lrr[j] = (unsigned char)r;
        atomicAdd(&h[r], 1);
    }
    __syncthreads();
    if (t == 0) {                       // serial scan (R<=256, ~cheap)
        int o = 0;
        for (int r = 0; r < R; r++) { lofs[r] = o; o += h[r]; }
        lofs[R] = o;
    }
    __syncthreads();
    if (t < R && h[t] > 0) gbase[t] = atomicAdd(&cursors[t], h[t]);
    __syncthreads();
    for (int j = t; j < m; j += BTPB) {
        int r = lrr[j];
        int sl = lofs[r] + atomicAdd(&c2[r], 1);
        stage[sl] = lpack[j];
    }
    __syncthreads();
    for (int j = t; j < m; j += BTPB) {     // dense copy, bsearch segment
        int lo = 0, hi = R;
        while (hi - lo > 1) {
            int mid = (lo + hi) >> 1;
            if (lofs[mid] <= j) lo = mid; else hi = mid;
        }
        buckets[gbase[lo] + (j - lofs[lo])] = stage[j];
    }
}

// One block per range: LDS histogram -> scan -> permute. Emits csr (src sorted
// by dst), cnt_i (per-node degree w/o self-loop), rowptr (global csr offsets).
__global__ __launch_bounds__(SORT_TPB) void k_sort(const unsigned* __restrict__ bkt,
                                                   const int* __restrict__ boff,
                                                   const int* __restrict__ blen,
                                                   unsigned* __restrict__ csr,
                                                   int* __restrict__ cnt_i,
                                                   int* __restrict__ rowptr) {
    __shared__ int cnt[S];
    __shared__ int cur[S];
    __shared__ int wtot[SORT_TPB / 64], wpre[SORT_TPB / 64];
    int r = blockIdx.x;
    int t = threadIdx.x;            // SORT_TPB == S
    cnt[t] = 0;
    __syncthreads();
    const unsigned* b = bkt + boff[r];
    int len = blen[r];
    for (int i = t; i < len; i += SORT_TPB)          // A: histogram
        atomicAdd(&cnt[b[i] >> 18], 1);
    __syncthreads();
    int v = cnt[t];                                   // B: exclusive scan
    int p = v;
    for (int o = 1; o < 64; o <<= 1) {
        int u = __shfl_up(p, o);
        if ((t & 63) >= o) p += u;
    }
    if ((t & 63) == 63) wtot[t >> 6] = p;
    __syncthreads();
    if (t == 0) {
        int a = 0;
        for (int w = 0; w < SORT_TPB / 64; w++) { wpre[w] = a; a += wtot[w]; }
    }
    __syncthreads();
    int excl = p - v + wpre[t >> 6];
    rowptr[r * S + t] = boff[r] + excl;
    cnt_i[r * S + t] = v;
    cur[t] = excl;
    __syncthreads();
    for (int i = t; i < len; i += SORT_TPB) {         // C: permute
        unsigned pk = b[i];
        int pos = atomicAdd(&cur[pk >> 18], 1);
        csr[boff[r] + pos] = pk & 0x3FFFFu;
    }
}

__global__ void k_dinv(const int* __restrict__ cnt_i, const float* __restrict__ x,
                       float* __restrict__ dinv, float* __restrict__ y, int n) {
    int i = blockIdx.x * blockDim.x + threadIdx.x;
    if (i < n) {
        float d = rsqrtf((float)cnt_i[i] + 1.0f);   // +1: self-loop
        dinv[i] = d;
        y[i] = x[i] * d;
    }
}

// Wave-per-node segment sum + fused epilogue. L=1: GCN1+ReLU+W2 -> z~ ; L=2: out.
template <int L>
__global__ __launch_bounds__(ATPB) void k_agg(const unsigned* __restrict__ csr,
                                              const int* __restrict__ rowptr,
                                              const int* __restrict__ cnt_i,
                                              const float* __restrict__ dinv,
                                              const float* __restrict__ val,
                                              float* __restrict__ outv,
                                              const float* __restrict__ W1,
                                              const float* __restrict__ b1,
                                              const float* __restrict__ W2,
                                              const float* __restrict__ b2,
                                              int n, int f) {
    int wid = blockIdx.x * (ATPB / 64) + (threadIdx.x >> 6);
    int lane = threadIdx.x & 63;
    if (wid >= n) return;
    int base = rowptr[wid];
    int len = cnt_i[wid];
    float s = 0.0f;
    for (int k = lane; k < len; k += 64)
        s += val[csr[base + k]];
    for (int o = 32; o > 0; o >>= 1) s += __shfl_xor(s, o);
    float dv = dinv[wid];
    float agg = dv * (s + val[wid]);   // + self-loop term
    float res;
    if (L == 1) {
        float h2 = 0.0f;
        for (int j = 0; j < f; j++) {
            float h = W1[j] * agg + b1[j];
            h2 += fmaxf(h, 0.0f) * W2[j];
        }
        res = h2 * dv;                 // z~ = h2 * dinv
    } else {
        res = agg + b2[0];
    }
    if (lane == 0) outv[wid] = res;
}

// =============== fallback (R5-proven): binned LDS-atomic scatter =============
#define FS 8192
#define FLOG_S 13
#define FMAXC 32
#define FSTPB 512

template <bool DEG>
__global__ __launch_bounds__(FSTPB) void f_scat(const unsigned* __restrict__ buckets,
                                                const int* __restrict__ boff,
                                                const int* __restrict__ blen,
                                                const float* __restrict__ val,
                                                float* __restrict__ partials, int bpr) {
    __shared__ float acc[FS];
    int t = threadIdx.x;
    int r = blockIdx.x / bpr;
    int c = blockIdx.x - r * bpr;
    float4* acc4 = (float4*)acc;
    for (int j = t; j < FS / 4; j += FSTPB) acc4[j] = make_float4(0.f, 0.f, 0.f, 0.f);
    __syncthreads();
    const unsigned* bk = buckets + boff[r];
    int len = blen[r];
    int stride = bpr * FSTPB;
    for (int i = c * FSTPB + t; i < len; i += stride) {
        unsigned p = bk[i];
        unsafeAtomicAdd(&acc[p >> 18], DEG ? 1.0f : val[p & 0x3FFFFu]);
    }
    __syncthreads();
    float4* out4 = (float4*)(partials + (size_t)blockIdx.x * FS);
    for (int j = t; j < FS / 4; j += FSTPB) out4[j] = acc4[j];
}

__device__ inline float f_red(const float* __restrict__ partials, int i, int bpr) {
    int r = i >> FLOG_S;
    int slot = i & (FS - 1);
    const float* p = partials + (size_t)r * bpr * FS + slot;
    float s = 0.0f;
    for (int c = 0; c < bpr; c++) s += p[(size_t)c * FS];
    return s;
}

__global__ void f_red_dinv(const float* __restrict__ partials, int bpr,
                           const float* __restrict__ x, float* __restrict__ dinv,
                           float* __restrict__ y, int n) {
    int i = blockIdx.x * blockDim.x + threadIdx.x;
    if (i < n) {
        float d = rsqrtf(f_red(partials, i, bpr) + 1.0f);
        dinv[i] = d;
        y[i] = x[i] * d;
    }
}

__global__ void f_red_node(const float* __restrict__ partials, int bpr,
                           const float* __restrict__ dinv, const float* __restrict__ y,
                           float* __restrict__ z,
                           const float* __restrict__ W1, const float* __restrict__ b1,
                           const float* __restrict__ W2, int n, int f) {
    int i = blockIdx.x * blockDim.x + threadIdx.x;
    if (i < n) {
        float agg = dinv[i] * (f_red(partials, i, bpr) + y[i]);
        float h2 = 0.0f;
        for (int j = 0; j < f; j++) {
            float h = W1[j] * agg + b1[j];
            h2 += fmaxf(h, 0.0f) * W2[j];
        }
        z[i] = h2 * dinv[i];
    }
}

__global__ void f_red_out(const float* __restrict__ partials, int bpr,
                          const float* __restrict__ dinv, const float* __restrict__ z,
                          const float* __restrict__ b2, float* __restrict__ out, int n) {
    int i = blockIdx.x * blockDim.x + threadIdx.x;
    if (i < n) out[i] = dinv[i] * (f_red(partials, i, bpr) + z[i]) + b2[0];
}

__global__ __launch_bounds__(BTPB) void f_bin(const int* __restrict__ dst,
                                              const int* __restrict__ src, int e,
                                              int R, int* __restrict__ cursors,
                                              unsigned* __restrict__ buckets) {
    __shared__ unsigned lpack[CHUNK];
    __shared__ unsigned char lrr[CHUNK];
    __shared__ unsigned stage[CHUNK];
    __shared__ int h[RMAX], lofs[RMAX + 1], gbase[RMAX], c2[RMAX];
    int t = threadIdx.x;
    int b0 = blockIdx.x * CHUNK;
    int m = min(CHUNK, e - b0);
    if (t < RMAX) { h[t] = 0; c2[t] = 0; }
    __syncthreads();
    for (int j = t; j < m; j += BTPB) {
        int d = dst[b0 + j];
        int s = src[b0 + j];
        int r = d >> FLOG_S;
        lpack[j] = ((unsigned)(d - (r << FLOG_S)) << 18) | (unsigned)s;
        lrr[j] = (unsigned char)r;
        atomicAdd(&h[r], 1);
    }
    __syncthreads();
    if (t == 0) {
        int o = 0;
        for (int r = 0; r < R; r++) { lofs[r] = o; o += h[r]; }
        lofs[R] = o;
    }
    __syncthreads();
    if (t < R && h[t] > 0) gbase[t] = atomicAdd(&cursors[t], h[t]);
    __syncthreads();
    for (int j = t; j < m; j += BTPB) {
        int r = lrr[j];
        int sl = lofs[r] + atomicAdd(&c2[r], 1);
        stage[sl] = lpack[j];
    }
    __syncthreads();
    for (int j = t; j < m; j += BTPB) {
        int lo = 0, hi = R;
        while (hi - lo > 1) {
            int mid = (lo + hi) >> 1;
            if (lofs[mid] <= j) lo = mid; else hi = mid;
        }
        buckets[gbase[lo] + (j - lofs[lo])] = stage[j];
    }
}

__global__ __launch_bounds__(TPB) void f_count(const int* __restrict__ dst, int e,
                                               int R, int* __restrict__ ghist) {
    __shared__ int h[RMAX];
    int t = threadIdx.x;
    if (t < RMAX) h[t] = 0;
    __syncthreads();
    int stride = gridDim.x * blockDim.x;
    for (int i = blockIdx.x * blockDim.x + t; i < e; i += stride)
        atomicAdd(&h[dst[i] >> FLOG_S], 1);
    __syncthreads();
    if (t < R && h[t]) atomicAdd(&ghist[t], h[t]);
}

extern "C" void kernel_launch(void* const* d_in, const int* in_sizes, int n_in,
                              void* d_out, int out_size, void* d_ws, size_t ws_size,
                              hipStream_t stream) {
    const float* x  = (const float*)d_in[0];
    const int*   ei = (const int*)d_in[1];
    const float* W1 = (const float*)d_in[2];
    const float* b1 = (const float*)d_in[3];
    const float* W2 = (const float*)d_in[4];
    const float* b2 = (const float*)d_in[5];

    int n = in_sizes[0];        // 200000
    int e = in_sizes[1] / 2;    // 12.8M
    int f = in_sizes[2];        // 16

    const int* src = ei;
    const int* dst = ei + e;
    float* out = (float*)d_out;

    int gn = (n + TPB - 1) / TPB;
    size_t words = ws_size / 4;

    // ---- CSR-path layout (words) ----
    int R = (n + S - 1) >> LOG_S;                    // 196
    size_t o_A    = 0;                               // dinv (n)
    size_t o_B    = o_A + n;                         // y    (n)
    size_t o_D    = o_B + n;                         // z~   (n)
    size_t o_hist = o_D + n;
    size_t o_boff = o_hist + RMAX;
    size_t o_blen = o_boff + RMAX + 1;
    size_t o_cur  = o_blen + RMAX;
    size_t o_bkt  = (o_cur + RMAX + 3) & ~(size_t)3;
    size_t bkcap  = (size_t)e + 4 * (size_t)RMAX;
    size_t o_csr  = o_bkt + bkcap;
    size_t o_cnt  = o_csr + bkcap;
    size_t o_row  = o_cnt + (size_t)R * S;
    size_t need   = o_row + (size_t)R * S + 1;

    float* A = (float*)d_ws + o_A;
    float* B = (float*)d_ws + o_B;
    float* D = (float*)d_ws + o_D;
    int*   hist = (int*)d_ws + o_hist;
    int*   boff = (int*)d_ws + o_boff;
    int*   blen = (int*)d_ws + o_blen;
    int*   cur  = (int*)d_ws + o_cur;

    if (R <= RMAX && n <= (1 << 18) && words >= need) {
        unsigned* bkt = (unsigned*)d_ws + o_bkt;
        unsigned* csr = (unsigned*)d_ws + o_csr;
        int* cnt_i  = (int*)d_ws + o_cnt;
        int* rowptr = (int*)d_ws + o_row;
        int gbin = (e + CHUNK - 1) / CHUNK;
        int ga = (n + (ATPB / 64) - 1) / (ATPB / 64);
        k_zero<<<1, RMAX, 0, stream>>>(hist, RMAX);
        k_count<<<512, TPB, 0, stream>>>(dst, e, R, hist);
        k_scan<<<1, 64, 0, stream>>>(hist, R, boff, blen, cur);
        k_bin<<<gbin, BTPB, 0, stream>>>(dst, src, e, R, cur, bkt);
        k_sort<<<R, SORT_TPB, 0, stream>>>(bkt, boff, blen, csr, cnt_i, rowptr);
        k_dinv<<<gn, TPB, 0, stream>>>(cnt_i, x, A, B, n);
        k_agg<1><<<ga, ATPB, 0, stream>>>(csr, rowptr, cnt_i, A, B, D,
                                          W1, b1, W2, b2, n, f);
        k_agg<2><<<ga, ATPB, 0, stream>>>(csr, rowptr, cnt_i, A, D, out,
                                          W1, b1, W2, b2, n, f);
        return;
    }

    // ---- fallback: R5-proven binned LDS-atomic scatter ----
    int FR = (n + FS - 1) >> FLOG_S;                 // 25
    size_t p_bkt  = (o_cur + RMAX + 3) & ~(size_t)3;
    size_t p_part = p_bkt + bkcap;
    int bpr = 0;
    if (words > p_part) {
        size_t per_c = (size_t)FR * FS;
        size_t m = (words - p_part) / per_c;
        bpr = (int)(m > FMAXC ? FMAXC : m);
    }
    unsigned* bkt = (unsigned*)d_ws + p_bkt;
    float* partials = (float*)d_ws + p_part;
    int gs = FR * bpr;
    int gbin = (e + CHUNK - 1) / CHUNK;
    k_zero<<<1, RMAX, 0, stream>>>(hist, RMAX);
    f_count<<<512, TPB, 0, stream>>>(dst, e, FR, hist);
    k_scan<<<1, 64, 0, stream>>>(hist, FR, boff, blen, cur);
    f_bin<<<gbin, BTPB, 0, stream>>>(dst, src, e, FR, cur, bkt);
    f_scat<true><<<gs, FSTPB, 0, stream>>>(bkt, boff, blen, nullptr, partials, bpr);
    f_red_dinv<<<gn, TPB, 0, stream>>>(partials, bpr, x, A, B, n);
    f_scat<false><<<gs, FSTPB, 0, stream>>>(bkt, boff, blen, B, partials, bpr);
    f_red_node<<<gn, TPB, 0, stream>>>(partials, bpr, A, B, D, W1, b1, W2, n, f);
    f_scat<false><<<gs, FSTPB, 0, stream>>>(bkt, boff, blen, D, partials, bpr);
    f_red_out<<<gn, TPB, 0, stream>>>(partials, bpr, A, D, b2, out, n);
}

// Round 7
// 370.393 us; speedup vs baseline: 1.5122x; 1.5122x over previous
//
#include <hip/hip_runtime.h>

#define TPB 256            // node-pass / count block size
#define BTPB 512           // k_bin block size
#define STPB 512           // k_scat block size
#define LOG_S 13
#define S (1 << LOG_S)     // 8192-node range -> 32 KB int LDS acc
#define RMAX 32
#define CHUNK 4096         // edges per k_bin block
#define MAXC 32            // scatter c-splits per range
#define SCALEF 2097152.0f  // 2^21 fixed-point scale for value scatter
#define INV_SCALEF (1.0f / 2097152.0f)

// R6 insight: unsafeAtomicAdd(float*) on __shared__ showed 0 LDS bank
// conflicts under 64-lane random scatter (impossible via the ds pipe), while
// int atomicAdd kernels show millions -> the float path never used ds_add.
// Fix: accumulate in int fixed-point (2^21) with plain atomicAdd -> proven
// ds-pipe path. Deg pass adds exact 1s. Partials + reduces stay int-exact.

__global__ void k_zero(int* __restrict__ p, int m) {
    int i = blockIdx.x * blockDim.x + threadIdx.x;
    if (i < m) p[i] = 0;
}

__global__ __launch_bounds__(TPB) void k_count(const int* __restrict__ dst, int e,
                                               int R, int* __restrict__ ghist) {
    __shared__ int h[RMAX];
    int t = threadIdx.x;
    if (t < RMAX) h[t] = 0;
    __syncthreads();
    int e4 = e >> 2;
    const int4* d4p = (const int4*)dst;
    int stride = gridDim.x * blockDim.x;
    for (int i = blockIdx.x * blockDim.x + t; i < e4; i += stride) {
        int4 d = d4p[i];
        atomicAdd(&h[d.x >> LOG_S], 1);
        atomicAdd(&h[d.y >> LOG_S], 1);
        atomicAdd(&h[d.z >> LOG_S], 1);
        atomicAdd(&h[d.w >> LOG_S], 1);
    }
    for (int i = (e4 << 2) + blockIdx.x * blockDim.x + t; i < e; i += stride)
        atomicAdd(&h[dst[i] >> LOG_S], 1);
    __syncthreads();
    if (t < R && h[t]) atomicAdd(&ghist[t], h[t]);
}

__global__ void k_scan(const int* __restrict__ ghist, int R,
                       int* __restrict__ boff, int* __restrict__ blen,
                       int* __restrict__ cursors) {
    if (threadIdx.x == 0 && blockIdx.x == 0) {
        int off = 0;
        for (int r = 0; r < R; r++) {
            boff[r] = off;
            blen[r] = ghist[r];
            cursors[r] = off;
            off = (off + ghist[r] + 3) & ~3;   // 16B-aligned bucket bases
        }
        boff[R] = off;
    }
}

__global__ __launch_bounds__(BTPB) void k_bin(const int* __restrict__ dst,
                                              const int* __restrict__ src, int e,
                                              int R, int* __restrict__ cursors,
                                              unsigned* __restrict__ buckets) {
    __shared__ unsigned lpack[CHUNK];
    __shared__ unsigned char lrr[CHUNK];
    __shared__ unsigned stage[CHUNK];
    __shared__ int h[RMAX], lofs[RMAX + 1], gbase[RMAX], c2[RMAX];
    int t = threadIdx.x;
    int b0 = blockIdx.x * CHUNK;
    int m = min(CHUNK, e - b0);
    if (t < RMAX) { h[t] = 0; c2[t] = 0; }
    __syncthreads();
    for (int j = t; j < m; j += BTPB) {
        int d = dst[b0 + j];
        int s = src[b0 + j];
        int r = d >> LOG_S;
        lpack[j] = ((unsigned)(d - (r << LOG_S)) << 18) | (unsigned)s;
        lrr[j] = (unsigned char)r;
        atomicAdd(&h[r], 1);
    }
    __syncthreads();
    if (t < 64) {                      // wave-0 exclusive scan + reservation
        int hv = (t < R) ? h[t] : 0;
        int v = hv;
        for (int o = 1; o < 64; o <<= 1) {
            int u = __shfl_up(v, o);
            if (t >= o) v += u;
        }
        if (t < R) lofs[t] = v - hv;
        if (t == R - 1) lofs[R] = v;   // total = m
        if (t < R && hv > 0) gbase[t] = atomicAdd(&cursors[t], hv);
    }
    __syncthreads();
    for (int j = t; j < m; j += BTPB) {
        int r = lrr[j];
        int sl = lofs[r] + atomicAdd(&c2[r], 1);
        stage[sl] = lpack[j];
    }
    __syncthreads();
    for (int j = t; j < m; j += BTPB) {     // dense copy, bsearch segment
        int lo = 0, hi = R;
        while (hi - lo > 1) {
            int mid = (lo + hi) >> 1;
            if (lofs[mid] <= j) lo = mid; else hi = mid;
        }
        buckets[gbase[lo] + (j - lofs[lo])] = stage[j];
    }
}

// MODE 0: degree (+1 exact). MODE 1: value (+rint(val*2^21)).
template <int MODE>
__global__ __launch_bounds__(STPB) void k_scat(const unsigned* __restrict__ buckets,
                                               const int* __restrict__ boff,
                                               const int* __restrict__ blen,
                                               const float* __restrict__ val,
                                               int* __restrict__ partials, int bpr) {
    __shared__ int acc[S];
    int t = threadIdx.x;
    int r = blockIdx.x / bpr;
    int c = blockIdx.x - r * bpr;
    int4* acc4 = (int4*)acc;
    for (int j = t; j < S / 4; j += STPB) acc4[j] = make_int4(0, 0, 0, 0);
    __syncthreads();
    const unsigned* bk = buckets + boff[r];
    int len = blen[r];
    int len4 = len >> 2;
    const uint4* bk4 = (const uint4*)bk;
    int stride = bpr * STPB;
    for (int i = c * STPB + t; i < len4; i += stride) {
        uint4 p = bk4[i];
        if (MODE == 0) {
            atomicAdd(&acc[p.x >> 18], 1);
            atomicAdd(&acc[p.y >> 18], 1);
            atomicAdd(&acc[p.z >> 18], 1);
            atomicAdd(&acc[p.w >> 18], 1);
        } else {
            atomicAdd(&acc[p.x >> 18], (int)rintf(val[p.x & 0x3FFFFu] * SCALEF));
            atomicAdd(&acc[p.y >> 18], (int)rintf(val[p.y & 0x3FFFFu] * SCALEF));
            atomicAdd(&acc[p.z >> 18], (int)rintf(val[p.z & 0x3FFFFu] * SCALEF));
            atomicAdd(&acc[p.w >> 18], (int)rintf(val[p.w & 0x3FFFFu] * SCALEF));
        }
    }
    for (int k = (len4 << 2) + c * STPB + t; k < len; k += stride) {
        unsigned p = bk[k];
        if (MODE == 0) atomicAdd(&acc[p >> 18], 1);
        else atomicAdd(&acc[p >> 18], (int)rintf(val[p & 0x3FFFFu] * SCALEF));
    }
    __syncthreads();
    int4* out4 = (int4*)(partials + (size_t)blockIdx.x * S);   // [r][c][S]
    for (int j = t; j < S / 4; j += STPB) out4[j] = acc4[j];
}

__device__ inline int redp(const int* __restrict__ partials, int i, int bpr) {
    int r = i >> LOG_S;
    int slot = i & (S - 1);
    const int* p = partials + (size_t)r * bpr * S + slot;
    int s = 0;
    for (int c = 0; c < bpr; c++) s += p[(size_t)c * S];
    return s;
}

__global__ void k_red_dinv(const int* __restrict__ partials, int bpr,
                           const float* __restrict__ x, float* __restrict__ dinv,
                           float* __restrict__ y, int n) {
    int i = blockIdx.x * blockDim.x + threadIdx.x;
    if (i < n) {
        float deg = (float)redp(partials, i, bpr) + 1.0f;   // +1: self-loop
        float d = rsqrtf(deg);
        dinv[i] = d;
        y[i] = x[i] * d;
    }
}

__global__ void k_red_node(const int* __restrict__ partials, int bpr,
                           const float* __restrict__ dinv, const float* __restrict__ y,
                           float* __restrict__ z,
                           const float* __restrict__ W1, const float* __restrict__ b1,
                           const float* __restrict__ W2, int n, int f) {
    int i = blockIdx.x * blockDim.x + threadIdx.x;
    if (i < n) {
        float num = (float)redp(partials, i, bpr) * INV_SCALEF;
        float agg = dinv[i] * (num + y[i]);   // + y[i]: self-loop term
        float h2 = 0.0f;
        for (int j = 0; j < f; j++) {
            float h = W1[j] * agg + b1[j];
            h2 += fmaxf(h, 0.0f) * W2[j];
        }
        z[i] = h2 * dinv[i];
    }
}

__global__ void k_red_out(const int* __restrict__ partials, int bpr,
                          const float* __restrict__ dinv, const float* __restrict__ z,
                          const float* __restrict__ b2, float* __restrict__ out, int n) {
    int i = blockIdx.x * blockDim.x + threadIdx.x;
    if (i < n) {
        float num = (float)redp(partials, i, bpr) * INV_SCALEF;
        out[i] = dinv[i] * (num + z[i]) + b2[0];  // + z[i]: self-loop term
    }
}

// =============== minimal fallback: global-atomic path (R1-proven) ===========
__global__ void g_init(float* __restrict__ deg, float* __restrict__ num, int n) {
    int i = blockIdx.x * blockDim.x + threadIdx.x;
    if (i < n) { deg[i] = 1.0f; num[i] = 0.0f; }
}
__global__ void g_deg(const int* __restrict__ dst, float* __restrict__ deg, int e) {
    int i = blockIdx.x * blockDim.x + threadIdx.x;
    if (i < e) atomicAdd(deg + dst[i], 1.0f);
}
__global__ void g_dinv(const float* __restrict__ x, float* __restrict__ dd,
                       float* __restrict__ y, int n) {
    int i = blockIdx.x * blockDim.x + threadIdx.x;
    if (i < n) { float d = rsqrtf(dd[i]); dd[i] = d; y[i] = x[i] * d; }
}
__global__ void g_scatter(const int* __restrict__ src, const int* __restrict__ dst,
                          const float* __restrict__ val, float* __restrict__ num, int e) {
    int i = blockIdx.x * blockDim.x + threadIdx.x;
    if (i < e) atomicAdd(num + dst[i], val[src[i]]);
}
__global__ void g_node(const float* __restrict__ dinv, const float* __restrict__ y,
                       float* __restrict__ num, float* __restrict__ z,
                       const float* __restrict__ W1, const float* __restrict__ b1,
                       const float* __restrict__ W2, int n, int f) {
    int i = blockIdx.x * blockDim.x + threadIdx.x;
    if (i < n) {
        float agg = dinv[i] * (num[i] + y[i]);
        float h2 = 0.0f;
        for (int j = 0; j < f; j++) {
            float h = W1[j] * agg + b1[j];
            h2 += fmaxf(h, 0.0f) * W2[j];
        }
        z[i] = h2 * dinv[i];
        num[i] = 0.0f;
    }
}
__global__ void g_out(const float* __restrict__ dinv, const float* __restrict__ z,
                      const float* __restrict__ num, const float* __restrict__ b2,
                      float* __restrict__ out, int n) {
    int i = blockIdx.x * blockDim.x + threadIdx.x;
    if (i < n) out[i] = dinv[i] * (num[i] + z[i]) + b2[0];
}

extern "C" void kernel_launch(void* const* d_in, const int* in_sizes, int n_in,
                              void* d_out, int out_size, void* d_ws, size_t ws_size,
                              hipStream_t stream) {
    const float* x  = (const float*)d_in[0];
    const int*   ei = (const int*)d_in[1];
    const float* W1 = (const float*)d_in[2];
    const float* b1 = (const float*)d_in[3];
    const float* W2 = (const float*)d_in[4];
    const float* b2 = (const float*)d_in[5];

    int n = in_sizes[0];        // 200000
    int e = in_sizes[1] / 2;    // 12.8M
    int f = in_sizes[2];        // 16

    const int* src = ei;
    const int* dst = ei + e;
    float* out = (float*)d_out;

    int R  = (n + S - 1) >> LOG_S;                  // 25
    int gn = (n + TPB - 1) / TPB;
    size_t words = ws_size / 4;

    // ws layout in 4-byte words
    size_t o_A    = 0;                              // dinv (n)
    size_t o_B    = o_A + n;                        // y    (n)
    size_t o_D    = o_B + n;                        // z    (n)
    size_t o_hist = o_D + n;                        // RMAX
    size_t o_boff = o_hist + RMAX;                  // RMAX+1
    size_t o_blen = o_boff + RMAX + 1;              // RMAX
    size_t o_cur  = o_blen + RMAX;                  // RMAX
    size_t o_bkt  = (o_cur + RMAX + 3) & ~(size_t)3;
    size_t bkcap  = (size_t)e + 4 * (size_t)RMAX;
    size_t o_part = o_bkt + bkcap;                  // 16B-aligned (e%4==0)

    float* A = (float*)d_ws + o_A;
    float* B = (float*)d_ws + o_B;
    float* D = (float*)d_ws + o_D;
    int*   hist = (int*)d_ws + o_hist;
    int*   boff = (int*)d_ws + o_boff;
    int*   blen = (int*)d_ws + o_blen;
    int*   cur  = (int*)d_ws + o_cur;

    int bpr = 0;
    if (R <= RMAX && n <= (1 << 18) && words > o_part) {
        size_t per_c = (size_t)R * S;
        size_t m = (words - o_part) / per_c;
        bpr = (int)(m > MAXC ? MAXC : m);
    }

    if (bpr >= 4) {
        unsigned* bkt = (unsigned*)d_ws + o_bkt;
        int* partials = (int*)d_ws + o_part;
        int gs = R * bpr;                           // 25*32 = 800 blocks
        int gbin = (e + CHUNK - 1) / CHUNK;         // 3125
        k_zero<<<1, RMAX, 0, stream>>>(hist, RMAX);
        k_count<<<512, TPB, 0, stream>>>(dst, e, R, hist);
        k_scan<<<1, 64, 0, stream>>>(hist, R, boff, blen, cur);
        k_bin<<<gbin, BTPB, 0, stream>>>(dst, src, e, R, cur, bkt);
        k_scat<0><<<gs, STPB, 0, stream>>>(bkt, boff, blen, nullptr, partials, bpr);
        k_red_dinv<<<gn, TPB, 0, stream>>>(partials, bpr, x, A, B, n);
        k_scat<1><<<gs, STPB, 0, stream>>>(bkt, boff, blen, B, partials, bpr);
        k_red_node<<<gn, TPB, 0, stream>>>(partials, bpr, A, B, D, W1, b1, W2, n, f);
        k_scat<1><<<gs, STPB, 0, stream>>>(bkt, boff, blen, D, partials, bpr);
        k_red_out<<<gn, TPB, 0, stream>>>(partials, bpr, A, D, b2, out, n);
    } else {
        // fallback: global-atomic path (correct, slower)
        float* C = D + n;
        int ge = (e + TPB - 1) / TPB;
        g_init<<<gn, TPB, 0, stream>>>(A, C, n);
        g_deg<<<ge, TPB, 0, stream>>>(dst, A, e);
        g_dinv<<<gn, TPB, 0, stream>>>(x, A, B, n);
        g_scatter<<<ge, TPB, 0, stream>>>(src, dst, B, C, e);
        g_node<<<gn, TPB, 0, stream>>>(A, B, C, D, W1, b1, W2, n, f);
        g_scatter<<<ge, TPB, 0, stream>>>(src, dst, D, C, e);
        g_out<<<gn, TPB, 0, stream>>>(A, D, C, b2, out, n);
    }
}